// Round 1
// baseline (390.173 us; speedup 1.0000x reference)
//
#include <hip/hip_runtime.h>
#include <stdint.h>

typedef short bf16x8 __attribute__((ext_vector_type(8)));
typedef float f32x4 __attribute__((ext_vector_type(4)));

__device__ __forceinline__ unsigned short f2bf(float f) {
    union { float f; unsigned int u; } x; x.f = f;
    unsigned int r = x.u + 0x7FFFu + ((x.u >> 16) & 1u);
    return (unsigned short)(r >> 16);
}

// ---- weight prep: f32 [K][N] row-major -> bf16 transposed [N][K] in ws ----
// ws element offsets: w1e_t @0 (128x256), w2e_t @32768 (128x128),
//                     w1n_t @49152 (128x256), w2n_t @81920 (128x128)
__global__ void prep_weights(const float* __restrict__ w1e, const float* __restrict__ w2e,
                             const float* __restrict__ w1n, const float* __restrict__ w2n,
                             unsigned short* __restrict__ ws) {
    int idx = blockIdx.x * 256 + threadIdx.x;
    if (idx < 32768) {
        int n = idx >> 8, k = idx & 255;
        ws[idx] = f2bf(w1e[k * 128 + n]);
    } else if (idx < 49152) {
        int t = idx - 32768; int n = t >> 7, k = t & 127;
        ws[idx] = f2bf(w2e[k * 128 + n]);
    } else if (idx < 81920) {
        int t = idx - 49152; int n = t >> 8, k = t & 255;
        ws[idx] = f2bf(w1n[k * 128 + n]);
    } else if (idx < 98304) {
        int t = idx - 81920; int n = t >> 7, k = t & 127;
        ws[idx] = f2bf(w2n[k * 128 + n]);
    }
}

// ---- fused: gather-mean -> concat -> GEMM1+relu -> GEMM2+relu -> LN ----
// X: [64][256] bf16, swizzled (byte ^= (row&7)<<4), row stride 512 B
// Y: [64][128] bf16, swizzled, row stride 256 B
// O: [64][132] f32 (aliases X region)
__global__ __launch_bounds__(256, 2)
void cagnn_layer(int rows,
                 const float* __restrict__ self_feats,   // [rows][128]
                 const float* __restrict__ nbr_src,      // [*][128]
                 const int*   __restrict__ nbr_idx,      // [rows][16]
                 const unsigned short* __restrict__ w1t, // [128][256] bf16 (n-major)
                 const unsigned short* __restrict__ w2t, // [128][128] bf16 (n-major)
                 const float* __restrict__ b1,
                 const float* __restrict__ b2,
                 const float* __restrict__ gamma,
                 const float* __restrict__ beta,
                 float* __restrict__ out)                // [rows][128]
{
    __shared__ __align__(16) char lds[33792 + 16384];
    float* O = (float*)lds;                                  // [64][132]
    char*  Ybase = lds + 33792;                              // [64][128] bf16

    const int tid  = threadIdx.x;
    const int wid  = tid >> 6;
    const int lane = tid & 63;
    const int base = blockIdx.x * 64;

    // ---------- stage X: self (cols 0..127) + neighbor mean (cols 128..255) ----------
    {
        const int c0 = 2 * lane;
        for (int rr = wid; rr < 64; rr += 4) {
            const int row = base + rr;
            float sx = 0.f, sy = 0.f, ax = 0.f, ay = 0.f;
            if (row < rows) {
                const float2 v = *(const float2*)(self_feats + (size_t)row * 128 + c0);
                sx = v.x; sy = v.y;
                const int* nb = nbr_idx + (size_t)row * 16;
                #pragma unroll
                for (int k = 0; k < 16; ++k) {
                    const int j = nb[k];
                    const float2 u = *(const float2*)(nbr_src + (size_t)j * 128 + c0);
                    ax += u.x; ay += u.y;
                }
            }
            unsigned int ps = (unsigned int)f2bf(sx) | ((unsigned int)f2bf(sy) << 16);
            unsigned int pa = (unsigned int)f2bf(ax * 0.0625f) | ((unsigned int)f2bf(ay * 0.0625f) << 16);
            const int bs = (rr * 512 + c0 * 2) ^ ((rr & 7) << 4);
            const int bm = (rr * 512 + (128 + c0) * 2) ^ ((rr & 7) << 4);
            *(unsigned int*)(lds + bs) = ps;
            *(unsigned int*)(lds + bm) = pa;
        }
    }

    const int n0 = wid * 32;     // wave's output-col base
    const int bn = lane & 15;    // n (or m) index within 16-tile
    const int kg = lane >> 4;    // k-group 0..3

    // ---------- preload B1 fragments (held in VGPRs) ----------
    bf16x8 B1[8][2];
    #pragma unroll
    for (int ks = 0; ks < 8; ++ks)
        #pragma unroll
        for (int nt = 0; nt < 2; ++nt)
            B1[ks][nt] = *(const bf16x8*)(w1t + (n0 + nt * 16 + bn) * 256 + ks * 32 + kg * 8);

    __syncthreads();

    // ---------- GEMM1: [64,256] @ [256,128] ----------
    f32x4 acc[4][2];
    #pragma unroll
    for (int m = 0; m < 4; ++m)
        #pragma unroll
        for (int nt = 0; nt < 2; ++nt)
            acc[m][nt] = (f32x4){0.f, 0.f, 0.f, 0.f};

    #pragma unroll
    for (int ks = 0; ks < 8; ++ks) {
        bf16x8 a[4];
        #pragma unroll
        for (int m = 0; m < 4; ++m) {
            const int row = m * 16 + bn;
            const int byte = (row * 512 + ks * 64 + kg * 16) ^ ((row & 7) << 4);
            a[m] = *(const bf16x8*)(lds + byte);
        }
        #pragma unroll
        for (int m = 0; m < 4; ++m)
            #pragma unroll
            for (int nt = 0; nt < 2; ++nt)
                acc[m][nt] = __builtin_amdgcn_mfma_f32_16x16x32_bf16(a[m], B1[ks][nt], acc[m][nt], 0, 0, 0);
    }

    // ---------- bias1 + relu -> Y (bf16, swizzled) ----------
    float b1v[2] = { b1[n0 + bn], b1[n0 + 16 + bn] };
    #pragma unroll
    for (int m = 0; m < 4; ++m)
        #pragma unroll
        for (int nt = 0; nt < 2; ++nt)
            #pragma unroll
            for (int j = 0; j < 4; ++j) {
                const int row = m * 16 + kg * 4 + j;
                const int col = n0 + nt * 16 + bn;
                float v = fmaxf(acc[m][nt][j] + b1v[nt], 0.f);
                const int byte = (row * 256 + col * 2) ^ ((row & 7) << 4);
                *(unsigned short*)(Ybase + byte) = f2bf(v);
            }

    // preload B2 fragments
    bf16x8 B2[4][2];
    #pragma unroll
    for (int ks = 0; ks < 4; ++ks)
        #pragma unroll
        for (int nt = 0; nt < 2; ++nt)
            B2[ks][nt] = *(const bf16x8*)(w2t + (n0 + nt * 16 + bn) * 128 + ks * 32 + kg * 8);

    __syncthreads();   // Y ready; also all X reads done (O may alias X after this)

    // ---------- GEMM2: [64,128] @ [128,128] ----------
    f32x4 acc2[4][2];
    #pragma unroll
    for (int m = 0; m < 4; ++m)
        #pragma unroll
        for (int nt = 0; nt < 2; ++nt)
            acc2[m][nt] = (f32x4){0.f, 0.f, 0.f, 0.f};

    #pragma unroll
    for (int ks = 0; ks < 4; ++ks) {
        bf16x8 a[4];
        #pragma unroll
        for (int m = 0; m < 4; ++m) {
            const int row = m * 16 + bn;
            const int byte = (row * 256 + ks * 64 + kg * 16) ^ ((row & 7) << 4);
            a[m] = *(const bf16x8*)(Ybase + byte);
        }
        #pragma unroll
        for (int m = 0; m < 4; ++m)
            #pragma unroll
            for (int nt = 0; nt < 2; ++nt)
                acc2[m][nt] = __builtin_amdgcn_mfma_f32_16x16x32_bf16(a[m], B2[ks][nt], acc2[m][nt], 0, 0, 0);
    }

    // ---------- bias2 + relu -> O (f32, stride 132) ----------
    float b2v[2] = { b2[n0 + bn], b2[n0 + 16 + bn] };
    #pragma unroll
    for (int m = 0; m < 4; ++m)
        #pragma unroll
        for (int nt = 0; nt < 2; ++nt)
            #pragma unroll
            for (int j = 0; j < 4; ++j) {
                const int row = m * 16 + kg * 4 + j;
                const int col = n0 + nt * 16 + bn;
                O[row * 132 + col] = fmaxf(acc2[m][nt][j] + b2v[nt], 0.f);
            }

    __syncthreads();

    // ---------- LayerNorm + writeout: 4 threads per row ----------
    {
        const int r    = tid >> 2;
        const int part = tid & 3;
        const float* Or = O + r * 132 + part * 32;
        float sum = 0.f, sq = 0.f;
        #pragma unroll
        for (int c = 0; c < 32; c += 4) {
            float4 v = *(const float4*)(Or + c);
            sum += v.x + v.y + v.z + v.w;
            sq  += v.x * v.x + v.y * v.y + v.z * v.z + v.w * v.w;
        }
        sum += __shfl_xor(sum, 1); sq += __shfl_xor(sq, 1);
        sum += __shfl_xor(sum, 2); sq += __shfl_xor(sq, 2);
        const float mean = sum * (1.f / 128.f);
        const float var  = sq * (1.f / 128.f) - mean * mean;
        const float rstd = rsqrtf(var + 1e-5f);
        const int row = base + r;
        if (row < rows) {
            float* op = out + (size_t)row * 128 + part * 32;
            const float* gp = gamma + part * 32;
            const float* bp = beta + part * 32;
            #pragma unroll
            for (int c = 0; c < 32; c += 4) {
                float4 v = *(const float4*)(Or + c);
                float4 g = *(const float4*)(gp + c);
                float4 b = *(const float4*)(bp + c);
                float4 o;
                o.x = (v.x - mean) * rstd * g.x + b.x;
                o.y = (v.y - mean) * rstd * g.y + b.y;
                o.z = (v.z - mean) * rstd * g.z + b.z;
                o.w = (v.w - mean) * rstd * g.w + b.w;
                *(float4*)(op + c) = o;
            }
        }
    }
}

extern "C" void kernel_launch(void* const* d_in, const int* in_sizes, int n_in,
                              void* d_out, int out_size, void* d_ws, size_t ws_size,
                              hipStream_t stream) {
    const int*   node_neighbors = (const int*)d_in[0];
    const int*   edge_neighbors = (const int*)d_in[1];
    const float* node_feats     = (const float*)d_in[2];
    const float* edge_feats     = (const float*)d_in[3];
    const float* W_edge_agg     = (const float*)d_in[4];
    const float* b_edge_agg     = (const float*)d_in[5];
    const float* W_edge_com     = (const float*)d_in[6];
    const float* b_edge_com     = (const float*)d_in[7];
    const float* W_node_agg     = (const float*)d_in[8];
    const float* b_node_agg     = (const float*)d_in[9];
    const float* W_node_com     = (const float*)d_in[10];
    const float* b_node_com     = (const float*)d_in[11];
    const float* ln_gamma       = (const float*)d_in[12];
    const float* ln_beta        = (const float*)d_in[13];

    const int N = in_sizes[2] / 128;   // 50000
    const int E = in_sizes[3] / 128;   // 100000

    float* out_nodes = (float*)d_out;
    float* out_edges = (float*)d_out + (size_t)N * 128;

    unsigned short* wsu = (unsigned short*)d_ws;

    prep_weights<<<384, 256, 0, stream>>>(W_edge_agg, W_edge_com, W_node_agg, W_node_com, wsu);

    // edge path -> out_edges
    cagnn_layer<<<(E + 63) / 64, 256, 0, stream>>>(
        E, edge_feats, edge_feats, edge_neighbors,
        wsu + 0, wsu + 32768, b_edge_agg, b_edge_com, ln_gamma, ln_beta, out_edges);

    // node path (gathers new edge feats from out_edges) -> out_nodes
    cagnn_layer<<<(N + 63) / 64, 256, 0, stream>>>(
        N, node_feats, out_edges, node_neighbors,
        wsu + 49152, wsu + 81920, b_node_agg, b_node_com, ln_gamma, ln_beta, out_nodes);
}